// Round 2
// baseline (166.677 us; speedup 1.0000x reference)
//
#include <hip/hip_runtime.h>

// Problem constants (from reference)
#define B_   1024
#define N_   256
#define E_   2304
#define FIN_ 6
#define VEC_ 26
#define STR_ 33   // f32 LDS row stride for h (33 -> bank spread, conflict-free scalar reads)

// ---- workspace layout (bytes) ----
#define WS_ROWPTR   0        // int[257]
#define WS_PACKED   1088     // int2[E_]  (src, norm-bits)
#define WS_FLAG     19520    // int: 1 = inputs are f32, 0 = bf16
#define WS_PERM     19584    // int[256]: degree-sorted node permutation
#define WS_F        20608    // float region (converted weights/biases)
// float offsets within wsF
#define OF_W1   0
#define OF_W2   192
#define OF_W3   1216
#define OF_WE   2240
#define OF_B1   3264
#define OF_B2   3296
#define OF_B3   3328
#define OF_BE   3360
#define OF_BPI  3392
#define OF_BVF  3904

__device__ __forceinline__ float bf2f(unsigned short u) {
    union { unsigned int i; float f; } x; x.i = ((unsigned int)u) << 16; return x.f;
}
__device__ __forceinline__ unsigned short f2bf(float f) {
    union { float f; unsigned int i; } x; x.f = f;
    unsigned int r = x.i + 0x7fffu + ((x.i >> 16) & 1u);   // RTNE
    return (unsigned short)(r >> 16);
}
__device__ __forceinline__ void bfx2(unsigned int u, float& lo, float& hi) {
    lo = __uint_as_float(u << 16);
    hi = __uint_as_float(u & 0xffff0000u);
}
__device__ __forceinline__ unsigned int packbf(float a, float b) {
    return (unsigned int)f2bf(a) | ((unsigned int)f2bf(b) << 16);
}

// ---------------------------------------------------------------------------
// Prep: dtype sniff, edge norms, dst-sorted CSR, degree-sorted node perm,
// weight/bias conversion to f32 in ws. One block, 256 threads.
// ---------------------------------------------------------------------------
__global__ __launch_bounds__(256) void prep_kernel(
    const void* __restrict__ gf_raw,
    const int* __restrict__ src, const int* __restrict__ dst,
    const void* W1r, const void* b1r, const void* W2r, const void* b2r,
    const void* W3r, const void* b3r, const void* Wer, const void* ber,
    const void* bpir, const void* bvfr,
    char* __restrict__ ws)
{
    __shared__ int   deg_o[N_], deg_i[N_];
    __shared__ float inv_o[N_], inv_i[N_];
    __shared__ int   scan[N_];
    __shared__ int   rp[N_ + 1];
    __shared__ int   cursor[N_];
    __shared__ int   bcnt[64], boff[64];
    __shared__ int   s_isf32;

    int*  row_ptr_g = (int*)(ws + WS_ROWPTR);
    int2* packed_g  = (int2*)(ws + WS_PACKED);
    int*  flag_g    = (int*)(ws + WS_FLAG);
    int*  perm_g    = (int*)(ws + WS_PERM);
    float* wsF      = (float*)(ws + WS_F);

    const int t = threadIdx.x;

    if (t == 0) s_isf32 = 0;
    deg_o[t] = 0; deg_i[t] = 0;
    if (t < 64) bcnt[t] = 0;
    __syncthreads();

    // dtype sniff: low u16 of each u32 is a sane bf16 iff inputs are bf16
    if (t < 64) {
        unsigned u = ((const unsigned int*)gf_raw)[t];
        unsigned e = (u >> 7) & 0xFFu;
        if (e < 100u || e > 140u) atomicOr(&s_isf32, 1);
    }
    for (int e = t; e < E_; e += 256) {
        atomicAdd(&deg_o[src[e]], 1);
        atomicAdd(&deg_i[dst[e]], 1);
    }
    __syncthreads();
    const int is_f32 = s_isf32;
    if (t == 0) flag_g[0] = is_f32;

    {
        int dO = deg_o[t], dI = deg_i[t];
        inv_o[t] = dO > 0 ? rsqrtf((float)dO) : 0.f;
        inv_i[t] = dI > 0 ? rsqrtf((float)dI) : 0.f;
        scan[t] = dI;
    }
    __syncthreads();
    // Hillis-Steele inclusive scan over deg_i
    for (int off = 1; off < N_; off <<= 1) {
        int v = (t >= off) ? scan[t - off] : 0;
        __syncthreads();
        scan[t] += v;
        __syncthreads();
    }
    rp[t + 1] = scan[t];
    if (t == 0) rp[0] = 0;
    __syncthreads();
    cursor[t]    = rp[t];
    row_ptr_g[t] = rp[t];
    if (t == 0) row_ptr_g[N_] = rp[N_];
    __syncthreads();
    for (int e = t; e < E_; e += 256) {
        int d = dst[e], s = src[e];
        int pos = atomicAdd(&cursor[d], 1);
        packed_g[pos] = make_int2(s, __float_as_int(inv_o[s] * inv_i[d]));
    }

    // degree-sorted node permutation (counting sort by in-degree)
    int dmy = deg_i[t]; if (dmy > 63) dmy = 63;
    atomicAdd(&bcnt[dmy], 1);
    __syncthreads();
    if (t == 0) { int run = 0; for (int i = 0; i < 64; ++i) { boff[i] = run; run += bcnt[i]; } }
    __syncthreads();
    {
        int pos = atomicAdd(&boff[dmy], 1);
        perm_g[pos] = t;
    }

    // weight/bias conversion -> f32 in ws
    auto conv = [&](const void* p, int off, int n) {
        if (is_f32) {
            const float* s = (const float*)p;
            for (int i = t; i < n; i += 256) wsF[off + i] = s[i];
        } else {
            const unsigned short* s = (const unsigned short*)p;
            for (int i = t; i < n; i += 256) wsF[off + i] = bf2f(s[i]);
        }
    };
    conv(W1r, OF_W1, 192);
    conv(W2r, OF_W2, 1024);
    conv(W3r, OF_W3, 1024);
    conv(Wer, OF_WE, 1024);
    conv(b1r, OF_B1, 32);
    conv(b2r, OF_B2, 32);
    conv(b3r, OF_B3, 32);
    conv(ber, OF_BE, 32);
    conv(bpir, OF_BPI, 512);
    conv(bvfr, OF_BVF, 512);
}

// ---------------------------------------------------------------------------
// Main: one block per batch element; 256 threads, one thread per node.
// Single in-place f32 LDS h-buffer; GEMM weights read uniformly from ws (f32).
// ---------------------------------------------------------------------------
__global__ __launch_bounds__(256) void main_kernel(
    const void* __restrict__ gf_raw, const void* __restrict__ vec_raw,
    const void* __restrict__ Wpi_raw, const void* __restrict__ Wvf_raw,
    const char* __restrict__ ws, void* __restrict__ out_raw)
{
    __shared__ __align__(16) float buf[N_ * STR_];   // per-node h rows (f32)
    __shared__ float part[8 * 33];
    __shared__ float hgl[32];
    __shared__ float comb[VEC_ + 32];

    const int t = threadIdx.x;
    const int b = blockIdx.x;

    const int*  row_ptr = (const int*)(ws + WS_ROWPTR);
    const int2* packed  = (const int2*)(ws + WS_PACKED);
    const int   is_f32  = ((const int*)(ws + WS_FLAG))[0];
    const int   node    = ((const int*)(ws + WS_PERM))[t];
    const float* wsF    = (const float*)(ws + WS_F);

    // stage node features (f32 into buf rows, 6 wide)
    if (is_f32) {
        const float* g = (const float*)gf_raw + (size_t)b * (N_ * FIN_);
        for (int i = t; i < N_ * FIN_; i += 256)
            buf[(i / FIN_) * STR_ + (i % FIN_)] = g[i];
    } else {
        const unsigned short* g = (const unsigned short*)gf_raw + (size_t)b * (N_ * FIN_);
        for (int i = t; i < N_ * FIN_; i += 256)
            buf[(i / FIN_) * STR_ + (i % FIN_)] = bf2f(g[i]);
    }
    const int beg = row_ptr[node], end = row_ptr[node + 1];
    __syncthreads();

    float o[32];

    // ---- layer 1: gather 6-wide, GEMM [6x32], relu ----
    {
        float a[FIN_] = {0.f, 0.f, 0.f, 0.f, 0.f, 0.f};
        for (int e = beg; e < end; ++e) {
            int2 p = packed[e];
            float w = __int_as_float(p.y);
            const float* hr = &buf[p.x * STR_];
#pragma unroll
            for (int k = 0; k < FIN_; ++k) a[k] += w * hr[k];
        }
#pragma unroll
        for (int j = 0; j < 32; ++j) o[j] = wsF[OF_B1 + j];
#pragma unroll
        for (int k = 0; k < FIN_; ++k) {
            float ak = a[k];
            const float* wr = &wsF[OF_W1 + k * 32];
#pragma unroll
            for (int j = 0; j < 32; ++j) o[j] += ak * wr[j];
        }
#pragma unroll
        for (int j = 0; j < 32; ++j) o[j] = fmaxf(o[j], 0.f);
    }
    __syncthreads();
    {
        float* row = &buf[node * STR_];
#pragma unroll
        for (int j = 0; j < 32; ++j) row[j] = o[j];
    }
    __syncthreads();

    // ---- layers 2 & 3: gather 32-wide, GEMM [32x32], relu, in-place ----
    for (int L = 0; L < 2; ++L) {
        float acc[32];
#pragma unroll
        for (int k = 0; k < 32; ++k) acc[k] = 0.f;
        for (int e = beg; e < end; ++e) {
            int2 p = packed[e];
            float w = __int_as_float(p.y);
            const float* hr = &buf[p.x * STR_];
#pragma unroll
            for (int k = 0; k < 32; ++k) acc[k] += w * hr[k];
        }
        const int ofW = (L == 0) ? OF_W2 : OF_W3;
        const int ofB = (L == 0) ? OF_B2 : OF_B3;
#pragma unroll
        for (int j = 0; j < 32; ++j) o[j] = wsF[ofB + j];
#pragma unroll
        for (int k = 0; k < 32; ++k) {
            float ak = acc[k];
            const float* wr = &wsF[ofW + k * 32];
#pragma unroll
            for (int j = 0; j < 32; ++j) o[j] += ak * wr[j];
        }
#pragma unroll
        for (int j = 0; j < 32; ++j) o[j] = fmaxf(o[j], 0.f);
        __syncthreads();
        {
            float* row = &buf[node * STR_];
#pragma unroll
            for (int j = 0; j < 32; ++j) row[j] = o[j];
        }
        __syncthreads();
    }

    // ---- mean over nodes -> hg[32] ----
    {
        int j = t & 31, g = t >> 5;
        float s = 0.f;
        for (int i = 0; i < 32; ++i) s += buf[(g * 32 + i) * STR_ + j];
        part[g * 33 + j] = s;
    }
    __syncthreads();
    if (t < 32) {
        float sum = 0.f;
#pragma unroll
        for (int g = 0; g < 8; ++g) sum += part[g * 33 + t];
        hgl[t] = sum * (1.0f / 256.0f);
    }
    __syncthreads();

    // ---- emb + comb ----
    if (t < 32) {
        float v = wsF[OF_BE + t];
#pragma unroll
        for (int j = 0; j < 32; ++j) v += hgl[j] * wsF[OF_WE + j * 32 + t];
        comb[VEC_ + t] = v;
    }
    if (t < VEC_) {
        comb[t] = is_f32 ? ((const float*)vec_raw)[b * VEC_ + t]
                         : bf2f(((const unsigned short*)vec_raw)[b * VEC_ + t]);
    }
    __syncthreads();

    // ---- head: thread t computes pi/vf outputs 2t, 2t+1 ----
    {
        float p0 = wsF[OF_BPI + 2 * t], p1 = wsF[OF_BPI + 2 * t + 1];
        float v0 = wsF[OF_BVF + 2 * t], v1 = wsF[OF_BVF + 2 * t + 1];
        if (is_f32) {
            const float2* Wp = (const float2*)Wpi_raw;   // [58][256] float2
            const float2* Wv = (const float2*)Wvf_raw;
            for (int k = 0; k < VEC_ + 32; ++k) {
                float c = comb[k];
                float2 a = Wp[k * 256 + t];
                p0 += c * a.x; p1 += c * a.y;
                float2 d = Wv[k * 256 + t];
                v0 += c * d.x; v1 += c * d.y;
            }
        } else {
            const unsigned int* Wp = (const unsigned int*)Wpi_raw;  // [58][256] u32 pairs
            const unsigned int* Wv = (const unsigned int*)Wvf_raw;
            for (int k = 0; k < VEC_ + 32; ++k) {
                float c = comb[k];
                float w0, w1;
                bfx2(Wp[k * 256 + t], w0, w1);
                p0 += c * w0; p1 += c * w1;
                bfx2(Wv[k * 256 + t], w0, w1);
                v0 += c * w0; v1 += c * w1;
            }
        }
        p0 = fmaxf(p0, 0.f); p1 = fmaxf(p1, 0.f);
        v0 = fmaxf(v0, 0.f); v1 = fmaxf(v1, 0.f);
        if (is_f32) {
            float2* outp = (float2*)out_raw;
            outp[b * 256 + t]          = make_float2(p0, p1);
            outp[262144 + b * 256 + t] = make_float2(v0, v1);
        } else {
            unsigned int* outp = (unsigned int*)out_raw;
            outp[b * 256 + t]          = packbf(p0, p1);
            outp[262144 + b * 256 + t] = packbf(v0, v1);
        }
    }
}

extern "C" void kernel_launch(void* const* d_in, const int* in_sizes, int n_in,
                              void* d_out, int out_size, void* d_ws, size_t ws_size,
                              hipStream_t stream)
{
    // d_in order: 0 gf, 1 vec, 2 src, 3 dst, 4 W1, 5 b1, 6 W2, 7 b2, 8 W3, 9 b3,
    //             10 W_emb, 11 b_emb, 12 W_pi, 13 b_pi, 14 W_vf, 15 b_vf
    prep_kernel<<<1, 256, 0, stream>>>(
        d_in[0], (const int*)d_in[2], (const int*)d_in[3],
        d_in[4], d_in[5], d_in[6], d_in[7], d_in[8], d_in[9],
        d_in[10], d_in[11], d_in[13], d_in[15],
        (char*)d_ws);
    main_kernel<<<B_, 256, 0, stream>>>(
        d_in[0], d_in[1], d_in[12], d_in[14],
        (const char*)d_ws, d_out);
}

// Round 5
// 138.388 us; speedup vs baseline: 1.2044x; 1.2044x over previous
//
#include <hip/hip_runtime.h>

// Problem constants (from reference) — ALL TENSORS ARE FLOAT32.
#define B_    1024
#define N_    256
#define E_    2304
#define FIN_  6
#define VEC_  26
#define STR_  36        // f32 LDS row stride (144 B, 16B-aligned -> ds_read_b128)

// ---- workspace layout (bytes) ----
#define WS_ROWPTR   0        // int[257]
#define WS_PACKED   1088     // int2[E_]  (src, f32 norm bits)
#define WS_PERM     19520    // int[256]

// ---------------------------------------------------------------------------
// Prep: CSR + edge norms + degree-sorted node perm. One block, 256 threads.
// (Verbatim the round-2 block-0 code that passed, minus dtype sniff / conv.)
// ---------------------------------------------------------------------------
__global__ __launch_bounds__(256) void prep_kernel(
    const int* __restrict__ src, const int* __restrict__ dst,
    char* __restrict__ ws)
{
    __shared__ int   deg_o[N_], deg_i[N_];
    __shared__ float inv_o[N_], inv_i[N_];
    __shared__ int   scan[N_];
    __shared__ int   rp[N_ + 1];
    __shared__ int   cursor[N_];
    __shared__ int   bcnt[64], boff[64];

    int*  row_ptr_g = (int*)(ws + WS_ROWPTR);
    int2* packed_g  = (int2*)(ws + WS_PACKED);
    int*  perm_g    = (int*)(ws + WS_PERM);

    const int t = threadIdx.x;

    deg_o[t] = 0; deg_i[t] = 0;
    if (t < 64) bcnt[t] = 0;
    __syncthreads();

    for (int e = t; e < E_; e += 256) {
        atomicAdd(&deg_o[src[e]], 1);
        atomicAdd(&deg_i[dst[e]], 1);
    }
    __syncthreads();
    {
        int dO = deg_o[t], dI = deg_i[t];
        inv_o[t] = dO > 0 ? rsqrtf((float)dO) : 0.f;
        inv_i[t] = dI > 0 ? rsqrtf((float)dI) : 0.f;
        scan[t] = dI;
    }
    __syncthreads();
    for (int off = 1; off < N_; off <<= 1) {
        int v = (t >= off) ? scan[t - off] : 0;
        __syncthreads();
        scan[t] += v;
        __syncthreads();
    }
    rp[t + 1] = scan[t];
    if (t == 0) rp[0] = 0;
    __syncthreads();
    cursor[t]    = rp[t];
    row_ptr_g[t] = rp[t];
    if (t == 0) row_ptr_g[N_] = rp[N_];
    __syncthreads();
    for (int e = t; e < E_; e += 256) {
        int d = dst[e], s = src[e];
        int pos = atomicAdd(&cursor[d], 1);
        packed_g[pos] = make_int2(s, __float_as_int(inv_o[s] * inv_i[d]));
    }

    // degree-sorted node permutation (counting sort by in-degree)
    int dmy = deg_i[t]; if (dmy > 63) dmy = 63;
    atomicAdd(&bcnt[dmy], 1);
    __syncthreads();
    if (t == 0) { int run = 0; for (int i = 0; i < 64; ++i) { boff[i] = run; run += bcnt[i]; } }
    __syncthreads();
    { int pos = atomicAdd(&boff[dmy], 1); perm_g[pos] = t; }
}

// ---------------------------------------------------------------------------
// Main: one block per batch element; 256 threads, one thread per node.
// f32 in/out. Weights read directly from global (f32, uniform -> scalar cache).
// In-place f32 LDS h-buffer, 16B-aligned rows, float4 gather/stores.
// ---------------------------------------------------------------------------
__global__ __launch_bounds__(256) void main_kernel(
    const float* __restrict__ gf,    // [B,N,6]
    const float* __restrict__ vec,   // [B,26]
    const float* __restrict__ W1, const float* __restrict__ b1,   // [6,32],[32]
    const float* __restrict__ W2, const float* __restrict__ b2,   // [32,32]
    const float* __restrict__ W3, const float* __restrict__ b3,
    const float* __restrict__ We, const float* __restrict__ be,   // [32,32]
    const float* __restrict__ Wpi, const float* __restrict__ bpi, // [58,512],[512]
    const float* __restrict__ Wvf, const float* __restrict__ bvf,
    const char* __restrict__ ws,
    float2* __restrict__ out)        // f32 pairs; pi @ [0,262144), vf @ +262144
{
    __shared__ __align__(16) float buf[N_ * STR_];   // 36,864 B
    __shared__ float part[8 * 33];
    __shared__ float hgl[32];
    __shared__ float comb[VEC_ + 32];

    const int t = threadIdx.x;
    const int b = blockIdx.x;

    const int*  row_ptr = (const int*)(ws + WS_ROWPTR);
    const int2* packed  = (const int2*)(ws + WS_PACKED);
    const int   node    = ((const int*)(ws + WS_PERM))[t];

    // stage node features, pad cols 6,7 with zero (enables float4 gather)
    {
        const float* g = gf + (size_t)b * (N_ * FIN_);
        for (int i = t; i < N_ * 8; i += 256) {
            int n = i >> 3, k = i & 7;
            buf[n * STR_ + k] = (k < FIN_) ? g[n * FIN_ + k] : 0.f;
        }
    }
    const int beg = row_ptr[node], end = row_ptr[node + 1];
    __syncthreads();

    float o[32];

    // ---- layer 1: gather (2x float4) + [6x32] GEMM + relu ----
    {
        float a[8] = {0,0,0,0,0,0,0,0};
        for (int e = beg; e < end; ++e) {
            int2 p = packed[e];
            float w = __int_as_float(p.y);
            const float4* hr = (const float4*)&buf[p.x * STR_];
            float4 c0 = hr[0], c1 = hr[1];
            a[0] += w * c0.x; a[1] += w * c0.y; a[2] += w * c0.z; a[3] += w * c0.w;
            a[4] += w * c1.x; a[5] += w * c1.y;
        }
#pragma unroll
        for (int j = 0; j < 32; ++j) o[j] = b1[j];
#pragma unroll
        for (int k = 0; k < FIN_; ++k) {
            float ak = a[k];
            const float* wr = &W1[k * 32];
#pragma unroll
            for (int j = 0; j < 32; ++j) o[j] += ak * wr[j];
        }
#pragma unroll
        for (int j = 0; j < 32; ++j) o[j] = fmaxf(o[j], 0.f);
    }
    __syncthreads();
    {
        float4* row = (float4*)&buf[node * STR_];
#pragma unroll
        for (int q = 0; q < 8; ++q) row[q] = make_float4(o[4*q], o[4*q+1], o[4*q+2], o[4*q+3]);
    }
    __syncthreads();

    // ---- layers 2 & 3: gather(32) via 8x float4 + [32x32] GEMM + relu ----
    for (int L = 0; L < 2; ++L) {
        float acc[32];
#pragma unroll
        for (int k = 0; k < 32; ++k) acc[k] = 0.f;
        for (int e = beg; e < end; ++e) {
            int2 p = packed[e];
            float w = __int_as_float(p.y);
            const float4* hr = (const float4*)&buf[p.x * STR_];
#pragma unroll
            for (int q = 0; q < 8; ++q) {
                float4 c = hr[q];
                acc[4*q]   += w * c.x;
                acc[4*q+1] += w * c.y;
                acc[4*q+2] += w * c.z;
                acc[4*q+3] += w * c.w;
            }
        }
        const float* Wl = (L == 0) ? W2 : W3;
        const float* Bl = (L == 0) ? b2 : b3;
#pragma unroll
        for (int j = 0; j < 32; ++j) o[j] = Bl[j];
#pragma unroll 8
        for (int k = 0; k < 32; ++k) {
            float ak = acc[k];
            const float* wr = &Wl[k * 32];
#pragma unroll
            for (int j = 0; j < 32; ++j) o[j] += ak * wr[j];
        }
#pragma unroll
        for (int j = 0; j < 32; ++j) o[j] = fmaxf(o[j], 0.f);
        __syncthreads();
        {
            float4* row = (float4*)&buf[node * STR_];
#pragma unroll
            for (int q = 0; q < 8; ++q) row[q] = make_float4(o[4*q], o[4*q+1], o[4*q+2], o[4*q+3]);
        }
        __syncthreads();
    }

    // ---- mean over nodes -> hg[32] ----
    {
        int j = t & 31, g = t >> 5;
        float s = 0.f;
        for (int i = 0; i < 32; ++i) s += buf[(g * 32 + i) * STR_ + j];
        part[g * 33 + j] = s;
    }
    __syncthreads();
    if (t < 32) {
        float sum = 0.f;
#pragma unroll
        for (int g = 0; g < 8; ++g) sum += part[g * 33 + t];
        hgl[t] = sum * (1.0f / 256.0f);
    }
    __syncthreads();

    // ---- emb + comb ----
    if (t < 32) {
        float v = be[t];
#pragma unroll
        for (int j = 0; j < 32; ++j) v += hgl[j] * We[j * 32 + t];
        comb[VEC_ + t] = v;
    }
    if (t < VEC_) comb[t] = vec[b * VEC_ + t];
    __syncthreads();

    // ---- head: thread t -> pi/vf outputs 2t, 2t+1 ----
    {
        float p0 = bpi[2 * t], p1 = bpi[2 * t + 1];
        float v0 = bvf[2 * t], v1 = bvf[2 * t + 1];
        const float2* Wp = (const float2*)Wpi;   // [58][256] float2
        const float2* Wv = (const float2*)Wvf;
        for (int k = 0; k < VEC_ + 32; ++k) {
            float c = comb[k];
            float2 a = Wp[k * 256 + t];
            p0 += c * a.x; p1 += c * a.y;
            float2 d = Wv[k * 256 + t];
            v0 += c * d.x; v1 += c * d.y;
        }
        out[b * 256 + t]          = make_float2(fmaxf(p0, 0.f), fmaxf(p1, 0.f));
        out[262144 + b * 256 + t] = make_float2(fmaxf(v0, 0.f), fmaxf(v1, 0.f));
    }
}

extern "C" void kernel_launch(void* const* d_in, const int* in_sizes, int n_in,
                              void* d_out, int out_size, void* d_ws, size_t ws_size,
                              hipStream_t stream)
{
    // d_in order: 0 gf, 1 vec, 2 src, 3 dst, 4 W1, 5 b1, 6 W2, 7 b2, 8 W3, 9 b3,
    //             10 W_emb, 11 b_emb, 12 W_pi, 13 b_pi, 14 W_vf, 15 b_vf
    prep_kernel<<<1, 256, 0, stream>>>(
        (const int*)d_in[2], (const int*)d_in[3], (char*)d_ws);
    main_kernel<<<B_, 256, 0, stream>>>(
        (const float*)d_in[0], (const float*)d_in[1],
        (const float*)d_in[4], (const float*)d_in[5],
        (const float*)d_in[6], (const float*)d_in[7],
        (const float*)d_in[8], (const float*)d_in[9],
        (const float*)d_in[10], (const float*)d_in[11],
        (const float*)d_in[12], (const float*)d_in[13],
        (const float*)d_in[14], (const float*)d_in[15],
        (const char*)d_ws, (float2*)d_out);
}